// Round 2
// baseline (529.793 us; speedup 1.0000x reference)
//
#include <hip/hip_runtime.h>

#define B_DIM 4096
#define IN_DIM 8192
#define HID_DIM 8192
#define NBLK 512
#define TPB 256

// ws layout: w_sum[IN_DIM] floats, then an int arrival counter.
// d_ws is poisoned to 0xAA before every timed launch -> must re-init each call.
__global__ void zero_kernel(float* __restrict__ ws) {
    int i = blockIdx.x * blockDim.x + threadIdx.x;
    if (i < IN_DIM) ws[i] = 0.0f;
    if (i == 0) *(int*)(ws + IN_DIM) = 0;
}

// Fused: (1) column-sum of W via per-thread accumulation + fp32 atomics,
// (2) software grid barrier (512 blocks = 2/CU co-resident; LDS 32KB -> 5/CU
// capacity, __launch_bounds__(256,2) caps VGPR so waves never limit),
// (3) stage w_sum into LDS with device-scope atomic loads (XCD-coherent),
// (4) GEMV: out[b] = 0.75 * x[b] . w_sum, one row per wave-half.
__global__ __launch_bounds__(TPB, 2) void fused_kernel(
    const float* __restrict__ x, const float* __restrict__ W,
    float* __restrict__ ws, float* __restrict__ out)
{
    __shared__ float lds_ws[IN_DIM];          // 32 KB
    float* w_sum = ws;
    int* counter = (int*)(ws + IN_DIM);

    const int tid = threadIdx.x;
    const int stride4 = IN_DIM / 4;

    // ---- Phase 1: colsum. block -> (col-group bx of 1024 cols, row-group by of 128 rows)
    {
        const int bx = blockIdx.x & 7;
        const int by = blockIdx.x >> 3;               // [0,64)
        const int col4 = bx * TPB + tid;              // float4 column index
        const float4* __restrict__ p =
            (const float4*)W + (size_t)(by * 128) * stride4 + col4;

        float4 acc = make_float4(0.f, 0.f, 0.f, 0.f);
#pragma unroll 8
        for (int r = 0; r < 128; ++r) {
            float4 v = p[(size_t)r * stride4];
            acc.x += v.x; acc.y += v.y; acc.z += v.z; acc.w += v.w;
        }
        const int col = col4 * 4;
        atomicAdd(&w_sum[col + 0], acc.x);
        atomicAdd(&w_sum[col + 1], acc.y);
        atomicAdd(&w_sum[col + 2], acc.z);
        atomicAdd(&w_sum[col + 3], acc.w);
    }

    // ---- Phase 2: grid barrier (arrive with release, spin relaxed)
    __threadfence();
    __syncthreads();
    if (tid == 0) {
        __hip_atomic_fetch_add(counter, 1, __ATOMIC_ACQ_REL, __HIP_MEMORY_SCOPE_AGENT);
        while (__hip_atomic_load(counter, __ATOMIC_RELAXED, __HIP_MEMORY_SCOPE_AGENT) < NBLK) {
            __builtin_amdgcn_s_sleep(8);
        }
    }
    __syncthreads();

    // ---- Phase 3: stage w_sum -> LDS with device-scope (coherent) loads
    for (int i = tid; i < IN_DIM; i += TPB)
        lds_ws[i] = __hip_atomic_load(&w_sum[i], __ATOMIC_RELAXED, __HIP_MEMORY_SCOPE_AGENT);
    __syncthreads();

    // ---- Phase 4: GEMV. 8 rows/block, 2 rows/wave.
    const int wave = tid >> 6;
    const int lane = tid & 63;
    const float4* __restrict__ ws4 = (const float4*)lds_ws;
#pragma unroll
    for (int rr = 0; rr < 2; ++rr) {
        const int row = blockIdx.x * 8 + wave * 2 + rr;
        const float4* __restrict__ xr = (const float4*)(x + (size_t)row * IN_DIM);
        float s = 0.f;
#pragma unroll 8
        for (int i = lane; i < stride4; i += 64) {
            float4 xv = xr[i];
            float4 wv = ws4[i];
            s += xv.x * wv.x + xv.y * wv.y + xv.z * wv.z + xv.w * wv.w;
        }
#pragma unroll
        for (int off = 32; off > 0; off >>= 1)
            s += __shfl_down(s, off);
        if (lane == 0) out[row] = s * 0.75f;
    }
}

extern "C" void kernel_launch(void* const* d_in, const int* in_sizes, int n_in,
                              void* d_out, int out_size, void* d_ws, size_t ws_size,
                              hipStream_t stream) {
    const float* x = (const float*)d_in[0];   // [B, IN]
    const float* W = (const float*)d_in[1];   // [HID, IN]
    float* out = (float*)d_out;               // [B, 1]
    float* ws = (float*)d_ws;                 // w_sum[IN] + counter

    zero_kernel<<<(IN_DIM + TPB - 1) / TPB, TPB, 0, stream>>>(ws);
    fused_kernel<<<NBLK, TPB, 0, stream>>>(x, W, ws, out);
}

// Round 3
// 435.528 us; speedup vs baseline: 1.2164x; 1.2164x over previous
//
#include <hip/hip_runtime.h>

#define B_DIM 4096
#define IN_DIM 8192
#define HID_DIM 8192
#define TPB 256

// Zero w_sum (in ws) and out (atomic target). Both are poisoned to 0xAA
// before every timed launch, so must re-init each call.
__global__ void zero_kernel(float* __restrict__ w_sum, float* __restrict__ out) {
    int i = blockIdx.x * blockDim.x + threadIdx.x;
    if (i < IN_DIM) w_sum[i] = 0.0f;
    if (i < B_DIM) out[i] = 0.0f;
}

// Column sums of W [HID, IN] row-major -> w_sum [IN].
// grid (8, 128): block covers 1024 cols (256 float4) x 64 rows.
// 1024 blocks = 4/CU; unroll 16 keeps 16 float4 loads in flight per lane.
__global__ void colsum_kernel(const float* __restrict__ W, float* __restrict__ w_sum) {
    const int col4 = blockIdx.x * TPB + threadIdx.x;       // float4 column index
    const int row0 = blockIdx.y * 64;
    const int stride4 = IN_DIM / 4;
    const float4* __restrict__ p = (const float4*)W + (size_t)row0 * stride4 + col4;

    float4 acc = make_float4(0.f, 0.f, 0.f, 0.f);
#pragma unroll 16
    for (int r = 0; r < 64; ++r) {
        float4 v = p[(size_t)r * stride4];
        acc.x += v.x; acc.y += v.y; acc.z += v.z; acc.w += v.w;
    }
    const int col = col4 * 4;
    atomicAdd(&w_sum[col + 0], acc.x);
    atomicAdd(&w_sum[col + 1], acc.y);
    atomicAdd(&w_sum[col + 2], acc.z);
    atomicAdd(&w_sum[col + 3], acc.w);
}

// GEMV: out[b] += 0.75 * (half-row dot). Two waves per row, each covering
// 1024 contiguous floats' worth of strided float4s (16 iters, fully unrolled
// -> 16 loads in flight). 8192 waves = 2048 blocks = 8 blocks/CU.
__global__ void gemv_kernel(const float* __restrict__ x,
                            const float* __restrict__ w_sum,
                            float* __restrict__ out) {
    const int gtid = blockIdx.x * TPB + threadIdx.x;
    const int wave = gtid >> 6;            // [0, 8192)
    const int lane = threadIdx.x & 63;
    const int row  = wave >> 1;            // [0, 4096)
    const int half = wave & 1;             // which half of the row

    const int base4 = half * (IN_DIM / 8); // float4 offset: 0 or 1024
    const float4* __restrict__ xr  = (const float4*)(x + (size_t)row * IN_DIM) + base4;
    const float4* __restrict__ ws4 = (const float4*)w_sum + base4;

    float s = 0.f;
#pragma unroll 16
    for (int it = 0; it < 16; ++it) {
        const int i = it * 64 + lane;
        float4 xv = xr[i];
        float4 wv = ws4[i];
        s += xv.x * wv.x + xv.y * wv.y + xv.z * wv.z + xv.w * wv.w;
    }
#pragma unroll
    for (int off = 32; off > 0; off >>= 1)
        s += __shfl_down(s, off);

    if (lane == 0) atomicAdd(&out[row], s * 0.75f);
}

extern "C" void kernel_launch(void* const* d_in, const int* in_sizes, int n_in,
                              void* d_out, int out_size, void* d_ws, size_t ws_size,
                              hipStream_t stream) {
    const float* x = (const float*)d_in[0];   // [B, IN]
    const float* W = (const float*)d_in[1];   // [HID, IN]
    float* out = (float*)d_out;               // [B, 1]
    float* w_sum = (float*)d_ws;              // [IN] scratch

    zero_kernel<<<(IN_DIM + TPB - 1) / TPB, TPB, 0, stream>>>(w_sum, out);

    dim3 g1(IN_DIM / (4 * TPB), HID_DIM / 64);   // (8, 128) = 1024 blocks
    colsum_kernel<<<g1, TPB, 0, stream>>>(W, w_sum);

    gemv_kernel<<<(B_DIM * 2 * 64) / TPB, TPB, 0, stream>>>(x, w_sum, out);
}